// Round 5
// baseline (137.351 us; speedup 1.0000x reference)
//
#include <hip/hip_runtime.h>
#include <hip/hip_bf16.h>
#include <math.h>
#include <stdint.h>

// ---------------------------------------------------------------------------
// SCF_GRUCell: spatial binning of 400k neighbors -> segment mean (64 bins x 48)
// -> FC(48x3072)+ReLU -> scalar-gate GRU (rt is dead code in the reference).
//
// Round 5: R4 proved contended global fp32 atomics pace at ~18G/s (memory-side
// RMW). Eliminate them: accum blocks write private slots (plain stores,
// R2-proven free); a parallel combine reduces 256 slots -> stage[8][3136] with
// plain stores; fc sums the 8 partials inline. Only remaining atomics: 25k
// count adds in bin (negligible at measured rate).
//
// ws float layout:
//   [0,64)       cnt[64]
//   [64,112)     fsp[48]
//   [128,25216)  stage[8][3136]
//   [25216, 25216+P*3200)  slots: per-block [64][49] histograms (col48 unused)
//   after slots: binrow[n] bytes (bin per hiddens row; 64 = dummy)
// ---------------------------------------------------------------------------

#define NBINS 64
#define ROWS 65
#define PAD 49
#define ENT (NBINS * PAD)   // 3136
#define SLOT 3200
#define GROUPS 8
#define CNT_OFF 0
#define FSP_OFF 64
#define STAGE_OFF 128
#define SLOT_OFF (STAGE_OFF + GROUPS * ENT)   // 25216
#define NBLK 256

__global__ __launch_bounds__(1024) void init_ws_kernel(
    float* __restrict__ ws, uint32_t* __restrict__ binrow32, int nwords,
    float* __restrict__ slots, int zero_slots, int slot_floats)
{
    int i = blockIdx.x * 1024 + threadIdx.x;
    int stride = gridDim.x * 1024;
    for (int k = i; k < 128; k += stride) ws[k] = 0.0f;            // cnt + fsp
    for (int k = i; k < nwords; k += stride) binrow32[k] = 0x40404040u;  // bin=64
    if (zero_slots)
        for (int k = i; k < slot_floats; k += stride) slots[k] = 0.0f;
}

__global__ __launch_bounds__(1024) void bin_kernel(
    const float2* __restrict__ loc_others,
    const float*  __restrict__ loc_agent,
    const int*    __restrict__ loc_other_index,
    uint8_t* __restrict__ binrow,
    float* __restrict__ cnt,      // [64]
    int n)
{
    __shared__ float s_cnt[ROWS];
    if (threadIdx.x < ROWS) s_cnt[threadIdx.x] = 0.0f;
    __syncthreads();

    const float ax = loc_agent[0];
    const float ay = loc_agent[1];

    int i = blockIdx.x * 1024 + threadIdx.x;
    if (i < n) {
        float2 p = loc_others[i];
        float cx = p.x - ax;
        float cy = p.y - ay;
        float d = sqrtf(cx * cx + cy * cy);
        int bin = NBINS;  // dummy
        if (d >= 0.5f && d <= 40.0f) {
            float ac = acosf(fminf(fmaxf(cx / d, -1.0f), 1.0f));
            float theta = (cy < 0.0f) ? (6.283185307179586f - ac) : ac;
            float uf = floorf((d - 0.5f) / 4.9375f);           // RADIUS_STEP
            float vf = floorf(theta / 0.7853981633974483f);    // THETA_STEP
            int u = (int)fminf(fmaxf(uf, 0.0f), 7.0f);
            int v = (int)fminf(fmaxf(vf, 0.0f), 7.0f);
            bin = u * 8 + v;
        }
        binrow[loc_other_index[i]] = (uint8_t)bin;
        unsafeAtomicAdd(&s_cnt[bin], 1.0f);
    }
    __syncthreads();
    if (threadIdx.x < NBINS && s_cnt[threadIdx.x] != 0.0f)
        unsafeAtomicAdd(&cnt[threadIdx.x], s_cnt[threadIdx.x]);
}

__global__ __launch_bounds__(1024) void accum_kernel(
    const float4* __restrict__ hflat,     // hiddens as float4[n*12]
    const uint8_t* __restrict__ binrow,   // [n]
    float* __restrict__ slots,            // [P][SLOT]
    int nf4, int P, int direct)
{
    __shared__ float s_sum[ROWS * PAD];   // 3185 floats
    for (int k = threadIdx.x; k < ROWS * PAD; k += 1024) s_sum[k] = 0.0f;
    __syncthreads();

    int j = blockIdx.x * 1024 + threadIdx.x;
    int stride = gridDim.x * 1024;
    for (; j < nf4; j += stride) {
        unsigned row = (unsigned)j / 12u;
        unsigned phase = (unsigned)j - row * 12u;
        int b = binrow[row];
        float4 h = hflat[j];
        float* dst = s_sum + b * PAD + phase * 4;
        unsafeAtomicAdd(dst + 0, h.x);
        unsafeAtomicAdd(dst + 1, h.y);
        unsafeAtomicAdd(dst + 2, h.z);
        unsafeAtomicAdd(dst + 3, h.w);
    }
    __syncthreads();

    // Epilogue: PLAIN coalesced stores to this block's private slot.
    float* dst = slots + (size_t)(blockIdx.x % P) * SLOT;
    if (direct) {
        for (int k = threadIdx.x; k < ENT; k += 1024) dst[k] = s_sum[k];
    } else {
        for (int k = threadIdx.x; k < ENT; k += 1024) {
            float v = s_sum[k];
            if (v != 0.0f) unsafeAtomicAdd(&dst[k], v);
        }
    }
}

__global__ __launch_bounds__(1024) void combine_kernel(
    const float* __restrict__ slots,   // [P][SLOT]
    float* __restrict__ stage,         // [GROUPS][ENT]
    int P)
{
    int t = blockIdx.x * 1024 + threadIdx.x;
    if (t >= GROUPS * ENT) return;
    unsigned g = (unsigned)t / (unsigned)ENT;
    unsigned k = (unsigned)t - g * ENT;
    int chunk = (P + GROUPS - 1) / GROUPS;
    int s0 = g * chunk;
    int s1 = s0 + chunk; if (s1 > P) s1 = P;
    float s = 0.0f;
#pragma unroll 8
    for (int b = s0; b < s1; ++b) s += slots[(size_t)b * SLOT + k];
    stage[t] = s;
}

__global__ __launch_bounds__(256) void fc_kernel(
    const float* __restrict__ W_fc,    // [48][3072]
    const float* __restrict__ b_fc,    // [48]
    const float* __restrict__ stage,   // [GROUPS][ENT]
    const float* __restrict__ cnt,     // [64]
    float* __restrict__ fsp)           // [48]
{
    int r = blockIdx.x;
    const float* w = W_fc + (size_t)r * (NBINS * 48);
    float partial = 0.0f;
    for (int k = threadIdx.x; k < NBINS * 48; k += 256) {
        int b = k / 48;
        int jj = k - b * 48;
        int e = b * PAD + jj;
        float s = 0.0f;
#pragma unroll
        for (int g = 0; g < GROUPS; ++g) s += stage[g * ENT + e];
        float c = cnt[b];
        float sp = (c > 1.0f) ? (s / c) : s;
        partial += w[k] * sp;
    }
    for (int off = 32; off >= 1; off >>= 1) partial += __shfl_down(partial, off, 64);
    __shared__ float red[4];
    if ((threadIdx.x & 63) == 0) red[threadIdx.x >> 6] = partial;
    __syncthreads();
    if (threadIdx.x == 0) {
        float s = red[0] + red[1] + red[2] + red[3];
        fsp[r] = fmaxf(s + b_fc[r], 0.0f);
    }
}

__global__ void gru_kernel(
    const float* __restrict__ feature_img,  // [1,32,80,80]
    const float* __restrict__ loc_agent,    // [2]
    const float* __restrict__ f_vel,        // [16]
    const float* __restrict__ fsp,          // [48] (ws)
    const float* __restrict__ hidden,       // [48]
    const float* __restrict__ w_iz, const float* __restrict__ w_hz,
    const float* __restrict__ b_iz, const float* __restrict__ b_hz,
    const float* __restrict__ w_in, const float* __restrict__ w_hn,
    const float* __restrict__ b_in, const float* __restrict__ b_hn,
    float* __restrict__ out)                // [48]
{
    int l = threadIdx.x;  // one wave
    int u0 = 40 - (int)loc_agent[1];
    int v0 = (int)loc_agent[0];
    int pix = u0 * 80 + v0;

    float pz = 0.0f, pn = 0.0f;
    for (int e = l; e < 96; e += 64) {
        float x;
        if (e < 32)      x = feature_img[e * 6400 + pix];
        else if (e < 48) x = f_vel[e - 32];
        else             x = fsp[e - 48];
        pz += x * w_iz[e];
        pn += x * w_in[e];
    }
    if (l < 48) {
        float h = hidden[l];
        pz += h * w_hz[l];
        pn += h * w_hn[l];
    }
    for (int off = 32; off >= 1; off >>= 1) {
        pz += __shfl_xor(pz, off, 64);
        pn += __shfl_xor(pn, off, 64);
    }
    float zt = 1.0f / (1.0f + expf(-(pz + b_iz[0] + b_hz[0])));
    float nt = tanhf(pn + b_in[0] + b_hn[0]);
    if (l < 48) out[l] = (1.0f - zt) * nt + zt * hidden[l];
}

extern "C" void kernel_launch(void* const* d_in, const int* in_sizes, int n_in,
                              void* d_out, int out_size, void* d_ws, size_t ws_size,
                              hipStream_t stream) {
    const float* loc_agent       = (const float*)d_in[0];
    const float* loc_others      = (const float*)d_in[1];
    const int*   loc_other_index = (const int*)d_in[2];
    const float* feature_img     = (const float*)d_in[3];
    const float* f_vel           = (const float*)d_in[4];
    const float* hiddens         = (const float*)d_in[5];
    const float* hidden          = (const float*)d_in[6];
    const float* W_fc            = (const float*)d_in[7];
    const float* b_fc            = (const float*)d_in[8];
    // d_in[9..12] = weight_ir / weight_hr / bias_ir / bias_hr : dead code
    const float* w_iz            = (const float*)d_in[13];
    const float* w_hz            = (const float*)d_in[14];
    const float* b_iz            = (const float*)d_in[15];
    const float* b_hz            = (const float*)d_in[16];
    const float* w_in            = (const float*)d_in[17];
    const float* w_hn            = (const float*)d_in[18];
    const float* b_in            = (const float*)d_in[19];
    const float* b_hn            = (const float*)d_in[20];

    float* ws    = (float*)d_ws;
    float* cnt   = ws + CNT_OFF;
    float* fsp   = ws + FSP_OFF;
    float* stage = ws + STAGE_OFF;
    float* slots = ws + SLOT_OFF;
    float* out   = (float*)d_out;

    int n = in_sizes[2];            // 400000 neighbors
    int nf4 = n * 12;               // hiddens as float4 count
    int nwords = (n + 3) / 4;       // binrow u32 words

    // How many private slots fit (slots + binrow after them)?
    long wfloats = (long)(ws_size / 4);
    long avail = (wfloats - SLOT_OFF - (long)nwords) / SLOT;
    int P = (int)(avail < 1 ? 1 : (avail > NBLK ? NBLK : avail));
    int direct = (P == NBLK) ? 1 : 0;
    uint8_t* binrow = (uint8_t*)(ws + SLOT_OFF + (size_t)P * SLOT);
    int slot_floats = P * SLOT;

    hipLaunchKernelGGL(init_ws_kernel, dim3(128), dim3(1024), 0, stream,
                       ws, (uint32_t*)binrow, nwords, slots, direct ? 0 : 1, slot_floats);
    hipLaunchKernelGGL(bin_kernel, dim3((n + 1023) / 1024), dim3(1024), 0, stream,
                       (const float2*)loc_others, loc_agent, loc_other_index,
                       binrow, cnt, n);
    hipLaunchKernelGGL(accum_kernel, dim3(NBLK), dim3(1024), 0, stream,
                       (const float4*)hiddens, binrow, slots, nf4, P, direct);
    hipLaunchKernelGGL(combine_kernel, dim3((GROUPS * ENT + 1023) / 1024), dim3(1024), 0, stream,
                       slots, stage, P);
    hipLaunchKernelGGL(fc_kernel, dim3(48), dim3(256), 0, stream,
                       W_fc, b_fc, stage, cnt, fsp);
    hipLaunchKernelGGL(gru_kernel, dim3(1), dim3(64), 0, stream,
                       feature_img, loc_agent, f_vel, fsp, hidden,
                       w_iz, w_hz, b_iz, b_hz, w_in, w_hn, b_in, b_hn, out);
}

// Round 6
// 124.490 us; speedup vs baseline: 1.1033x; 1.1033x over previous
//
#include <hip/hip_runtime.h>
#include <hip/hip_bf16.h>
#include <math.h>
#include <stdint.h>

// ---------------------------------------------------------------------------
// SCF_GRUCell: spatial binning of 400k neighbors -> segment mean (64 bins x 48)
// -> FC(48x3072)+ReLU -> scalar-gate GRU (rt is dead code in the reference).
//
// Round 6: R1-R5 isolated the pacer to LDS atomic lane-op throughput (~1 lane
// per cycle per CU for scattered ds_add). This version has ZERO LDS atomics:
// each wave owns a private LDS region [65][48]; per row, lanes 0..47 own
// column l (plain read+add+write, never a same-address collision), lane 48
// owns the count. hiddens is streamed coalesced (192B per wave-instr).
//
// ws float layout:
//   [0,48)                      fsp
//   [64, 64+32*3136)            stage[32][3136]  (3072 sums + 64 cnts)
//   [SLOT_OFF, +P*3200)         slots: per-block 3072 sums + 64 cnts
//   after slots:                binrow[n] bytes (bin per row; 64 = masked)
// ---------------------------------------------------------------------------

#define NBINS 64
#define ROWS 65
#define SUMR (ROWS * 48)        // 3120 floats per wave region
#define ENT 3136                // 3072 sums + 64 counts per slot
#define SLOT 3200
#define GROUPS 32
#define FSP_OFF 0
#define STAGE_OFF 64
#define SLOT_OFF (STAGE_OFF + GROUPS * ENT)   // 64 + 100352 = 100416
#define MAXBLK 768

__global__ __launch_bounds__(1024) void bin_kernel(
    const float2* __restrict__ loc_others,
    const float*  __restrict__ loc_agent,
    const int*    __restrict__ loc_other_index,
    uint8_t* __restrict__ binrow,
    int n)
{
    int i = blockIdx.x * 1024 + threadIdx.x;
    if (i >= n) return;
    const float ax = loc_agent[0];
    const float ay = loc_agent[1];
    float2 p = loc_others[i];
    float cx = p.x - ax;
    float cy = p.y - ay;
    float d = sqrtf(cx * cx + cy * cy);
    int bin = NBINS;  // dummy (masked)
    if (d >= 0.5f && d <= 40.0f) {
        float ac = acosf(fminf(fmaxf(cx / d, -1.0f), 1.0f));
        float theta = (cy < 0.0f) ? (6.283185307179586f - ac) : ac;
        float uf = floorf((d - 0.5f) / 4.9375f);           // RADIUS_STEP
        float vf = floorf(theta / 0.7853981633974483f);    // THETA_STEP
        int u = (int)fminf(fmaxf(uf, 0.0f), 7.0f);
        int v = (int)fminf(fmaxf(vf, 0.0f), 7.0f);
        bin = u * 8 + v;
    }
    binrow[loc_other_index[i]] = (uint8_t)bin;
}

__global__ __launch_bounds__(256) void accum_kernel(
    const float*   __restrict__ hiddens,   // [n][48]
    const uint8_t* __restrict__ binrow,    // [n]
    float* __restrict__ slots,             // [P][SLOT]
    int n, int nblocks)
{
    __shared__ float s_sum[4 * SUMR];      // 4 wave-private [65][48] = 48.75 KB
    __shared__ float s_cnt[4 * ROWS];
    for (int k = threadIdx.x; k < 4 * SUMR; k += 256) s_sum[k] = 0.0f;
    for (int k = threadIdx.x; k < 4 * ROWS; k += 256) s_cnt[k] = 0.0f;
    __syncthreads();

    const int wid = threadIdx.x >> 6;
    const int l   = threadIdx.x & 63;
    float* mysum = s_sum + wid * SUMR;
    float* mycnt = s_cnt + wid * ROWS;

    const int gw = blockIdx.x * 4 + wid;       // global wave id
    const int nw = nblocks * 4;
    const int chunk = (n + nw - 1) / nw;
    int r0 = gw * chunk;
    int r1 = r0 + chunk; if (r1 > n) r1 = n;

    for (int r = r0; r < r1; ++r) {
        int b = binrow[r];                     // broadcast load
        if (l < 48) {
            float h = hiddens[(size_t)r * 48 + l];   // coalesced 192B/wave
            mysum[b * 48 + l] += h;            // lane-owned column: no race
        } else if (l == 48) {
            mycnt[b] += 1.0f;                  // single lane: no race
        }
    }
    __syncthreads();

    // Block-combine 4 wave regions -> this block's slot (plain stores).
    float* dst = slots + (size_t)blockIdx.x * SLOT;
    for (int k = threadIdx.x; k < NBINS * 48; k += 256)
        dst[k] = s_sum[k] + s_sum[SUMR + k] + s_sum[2 * SUMR + k] + s_sum[3 * SUMR + k];
    if (threadIdx.x < NBINS)
        dst[3072 + threadIdx.x] = s_cnt[threadIdx.x] + s_cnt[ROWS + threadIdx.x]
                                + s_cnt[2 * ROWS + threadIdx.x] + s_cnt[3 * ROWS + threadIdx.x];
}

__global__ __launch_bounds__(1024) void combine_kernel(
    const float* __restrict__ slots,   // [P][SLOT]
    float* __restrict__ stage,         // [GROUPS][ENT]
    int P)
{
    int t = blockIdx.x * 1024 + threadIdx.x;
    if (t >= GROUPS * ENT) return;
    unsigned g = (unsigned)t / (unsigned)ENT;
    unsigned k = (unsigned)t - g * ENT;
    int chunk = (P + GROUPS - 1) / GROUPS;
    int s0 = g * chunk;
    int s1 = s0 + chunk; if (s1 > P) s1 = P;
    float s = 0.0f;
#pragma unroll 4
    for (int b = s0; b < s1; ++b) s += slots[(size_t)b * SLOT + k];
    stage[t] = s;
}

__global__ __launch_bounds__(256) void fc_kernel(
    const float* __restrict__ W_fc,    // [48][3072]
    const float* __restrict__ b_fc,    // [48]
    const float* __restrict__ stage,   // [GROUPS][ENT]
    float* __restrict__ fsp)           // [48]
{
    __shared__ float s_cnt[NBINS];
    if (threadIdx.x < NBINS) {
        float c = 0.0f;
#pragma unroll
        for (int g = 0; g < GROUPS; ++g) c += stage[g * ENT + 3072 + threadIdx.x];
        s_cnt[threadIdx.x] = c;
    }
    __syncthreads();

    int r = blockIdx.x;
    const float* w = W_fc + (size_t)r * (NBINS * 48);
    float partial = 0.0f;
    for (int k = threadIdx.x; k < NBINS * 48; k += 256) {
        float s = 0.0f;
#pragma unroll
        for (int g = 0; g < GROUPS; ++g) s += stage[g * ENT + k];
        float c = s_cnt[k / 48];
        float sp = (c > 1.0f) ? (s / c) : s;
        partial += w[k] * sp;
    }
    for (int off = 32; off >= 1; off >>= 1) partial += __shfl_down(partial, off, 64);
    __shared__ float red[4];
    if ((threadIdx.x & 63) == 0) red[threadIdx.x >> 6] = partial;
    __syncthreads();
    if (threadIdx.x == 0) {
        float s = red[0] + red[1] + red[2] + red[3];
        fsp[r] = fmaxf(s + b_fc[r], 0.0f);
    }
}

__global__ void gru_kernel(
    const float* __restrict__ feature_img,  // [1,32,80,80]
    const float* __restrict__ loc_agent,    // [2]
    const float* __restrict__ f_vel,        // [16]
    const float* __restrict__ fsp,          // [48] (ws)
    const float* __restrict__ hidden,       // [48]
    const float* __restrict__ w_iz, const float* __restrict__ w_hz,
    const float* __restrict__ b_iz, const float* __restrict__ b_hz,
    const float* __restrict__ w_in, const float* __restrict__ w_hn,
    const float* __restrict__ b_in, const float* __restrict__ b_hn,
    float* __restrict__ out)                // [48]
{
    int l = threadIdx.x;  // one wave
    int u0 = 40 - (int)loc_agent[1];
    int v0 = (int)loc_agent[0];
    int pix = u0 * 80 + v0;

    float pz = 0.0f, pn = 0.0f;
    for (int e = l; e < 96; e += 64) {
        float x;
        if (e < 32)      x = feature_img[e * 6400 + pix];
        else if (e < 48) x = f_vel[e - 32];
        else             x = fsp[e - 48];
        pz += x * w_iz[e];
        pn += x * w_in[e];
    }
    if (l < 48) {
        float h = hidden[l];
        pz += h * w_hz[l];
        pn += h * w_hn[l];
    }
    for (int off = 32; off >= 1; off >>= 1) {
        pz += __shfl_xor(pz, off, 64);
        pn += __shfl_xor(pn, off, 64);
    }
    float zt = 1.0f / (1.0f + expf(-(pz + b_iz[0] + b_hz[0])));
    float nt = tanhf(pn + b_in[0] + b_hn[0]);
    if (l < 48) out[l] = (1.0f - zt) * nt + zt * hidden[l];
}

extern "C" void kernel_launch(void* const* d_in, const int* in_sizes, int n_in,
                              void* d_out, int out_size, void* d_ws, size_t ws_size,
                              hipStream_t stream) {
    const float* loc_agent       = (const float*)d_in[0];
    const float* loc_others      = (const float*)d_in[1];
    const int*   loc_other_index = (const int*)d_in[2];
    const float* feature_img     = (const float*)d_in[3];
    const float* f_vel           = (const float*)d_in[4];
    const float* hiddens         = (const float*)d_in[5];
    const float* hidden          = (const float*)d_in[6];
    const float* W_fc            = (const float*)d_in[7];
    const float* b_fc            = (const float*)d_in[8];
    // d_in[9..12] = weight_ir / weight_hr / bias_ir / bias_hr : dead code
    const float* w_iz            = (const float*)d_in[13];
    const float* w_hz            = (const float*)d_in[14];
    const float* b_iz            = (const float*)d_in[15];
    const float* b_hz            = (const float*)d_in[16];
    const float* w_in            = (const float*)d_in[17];
    const float* w_hn            = (const float*)d_in[18];
    const float* b_in            = (const float*)d_in[19];
    const float* b_hn            = (const float*)d_in[20];

    float* ws    = (float*)d_ws;
    float* fsp   = ws + FSP_OFF;
    float* stage = ws + STAGE_OFF;
    float* slots = ws + SLOT_OFF;
    float* out   = (float*)d_out;

    int n = in_sizes[2];            // 400000 neighbors
    long nwords = (n + 3) / 4;      // binrow u32 words

    long wfloats = (long)(ws_size / 4);
    long avail = (wfloats - SLOT_OFF - nwords) / SLOT;
    int P = (int)(avail < 1 ? 1 : (avail > MAXBLK ? MAXBLK : avail));
    uint8_t* binrow = (uint8_t*)(ws + SLOT_OFF + (size_t)P * SLOT);

    hipLaunchKernelGGL(bin_kernel, dim3((n + 1023) / 1024), dim3(1024), 0, stream,
                       (const float2*)loc_others, loc_agent, loc_other_index,
                       binrow, n);
    hipLaunchKernelGGL(accum_kernel, dim3(P), dim3(256), 0, stream,
                       hiddens, binrow, slots, n, P);
    hipLaunchKernelGGL(combine_kernel, dim3((GROUPS * ENT + 1023) / 1024), dim3(1024), 0, stream,
                       slots, stage, P);
    hipLaunchKernelGGL(fc_kernel, dim3(48), dim3(256), 0, stream,
                       W_fc, b_fc, stage, fsp);
    hipLaunchKernelGGL(gru_kernel, dim3(1), dim3(64), 0, stream,
                       feature_img, loc_agent, f_vel, fsp, hidden,
                       w_iz, w_hz, b_iz, b_hz, w_in, w_hn, b_in, b_hn, out);
}